// Round 2
// baseline (420.310 us; speedup 1.0000x reference)
//
#include <hip/hip_runtime.h>
#include <hip/hip_cooperative_groups.h>

namespace cg = cooperative_groups;

#define N_IMG 4
#define E_DIM 16
#define P_PIX 320000
#define G_PIX (P_PIX / 4)       // 80000 float4 groups per image-channel
#define C_CLS 20
#define CK 19                   // classes 1..19 (IGNORE = 0)
#define NREP 8                  // LDS replica count for atomic binning
#define EG 4                    // channels per phase-1 block
#define NEG (E_DIM / EG)        // 4 channel groups
#define SL1 64                  // phase-1 pixel slices per (image, egroup)
#define R1 (G_PIX / SL1)        // 1250 g per phase-1 block (exact)
#define GRID_B (SL1 * NEG * N_IMG)   // 1024 blocks = 4 per CU exactly
#define SL2 (GRID_B / N_IMG)    // 256 phase-2 slices per image
#define R2 ((G_PIX + SL2 - 1) / SL2) // 313 (tail-checked)
#define MSTRIDE 17              // lmean stride: 20 labels -> 20 distinct banks
#define LSTRIDE (EG + 1)        // 5: e'=0..3 values, e'=4 count; x5 invertible mod 32

// ws layout (floats): sums[n][c][e], counts[n][c], loss
#define SUMS_OFF 0
#define CNT_OFF (N_IMG * C_CLS * E_DIM)       // 1280
#define LOSS_OFF (CNT_OFF + N_IMG * C_CLS)    // 1360
#define WS_FLOATS (LOSS_OFF + 1)

static_assert(G_PIX % SL1 == 0, "phase-1 slicing must be exact");
static_assert(GRID_B % N_IMG == 0, "phase-2 slicing");

// mode: 1 = phase-1 only, 2 = phase-2 only (fallback path), 3 = fused cooperative
__global__ __launch_bounds__(256, 4) void k_fused(const float* __restrict__ emb,
                                                  const int* __restrict__ target,
                                                  float* __restrict__ ws,
                                                  float* __restrict__ out,
                                                  int mode) {
    __shared__ float ls[C_CLS][NREP][LSTRIDE];   // 800 floats
    __shared__ float lmean[C_CLS * MSTRIDE];
    __shared__ float lw[C_CLS];
    __shared__ float red[256];

    const int tid = threadIdx.x;
    const int b = blockIdx.x;

    if (mode & 1) {
        // ---------- phase 1: per-class sums (EG channels) + counts via LDS binning ----------
        const int n = b & 3;
        const int eg = (b >> 2) & (NEG - 1);
        const int slice = b >> 4;                 // 0..63
        const int e0 = eg * EG;

        float* lsf = &ls[0][0][0];
        for (int i = tid; i < C_CLS * NREP * LSTRIDE; i += 256) lsf[i] = 0.f;
        __syncthreads();

        const float4* emb0 = (const float4*)emb + ((size_t)(n * E_DIM + e0)) * G_PIX;
        const int4* tgt4 = (const int4*)target + (size_t)n * G_PIX;
        const int r5 = (tid & (NREP - 1)) * LSTRIDE;

        const int g1 = (slice + 1) * R1;
        for (int g = slice * R1 + tid; g < g1; g += 256) {
            const int4 lb = tgt4[g];
            const float4 v0 = emb0[g];
            const float4 v1 = emb0[G_PIX + g];
            const float4 v2 = emb0[2 * G_PIX + g];
            const float4 v3 = emb0[3 * G_PIX + g];
            const int ax = lb.x * (NREP * LSTRIDE) + r5;
            const int ay = lb.y * (NREP * LSTRIDE) + r5;
            const int az = lb.z * (NREP * LSTRIDE) + r5;
            const int aw = lb.w * (NREP * LSTRIDE) + r5;
            atomicAdd(&lsf[ax + 0], v0.x); atomicAdd(&lsf[ax + 1], v1.x);
            atomicAdd(&lsf[ax + 2], v2.x); atomicAdd(&lsf[ax + 3], v3.x);
            atomicAdd(&lsf[ay + 0], v0.y); atomicAdd(&lsf[ay + 1], v1.y);
            atomicAdd(&lsf[ay + 2], v2.y); atomicAdd(&lsf[ay + 3], v3.y);
            atomicAdd(&lsf[az + 0], v0.z); atomicAdd(&lsf[az + 1], v1.z);
            atomicAdd(&lsf[az + 2], v2.z); atomicAdd(&lsf[az + 3], v3.z);
            atomicAdd(&lsf[aw + 0], v0.w); atomicAdd(&lsf[aw + 1], v1.w);
            atomicAdd(&lsf[aw + 2], v2.w); atomicAdd(&lsf[aw + 3], v3.w);
            if (eg == 0) {
                atomicAdd(&lsf[ax + EG], 1.f); atomicAdd(&lsf[ay + EG], 1.f);
                atomicAdd(&lsf[az + EG], 1.f); atomicAdd(&lsf[aw + EG], 1.f);
            }
        }
        __syncthreads();

        for (int i = tid; i < C_CLS * EG; i += 256) {
            const int c = i / EG, e1 = i % EG;
            float s = 0.f;
#pragma unroll
            for (int r = 0; r < NREP; r++) s += ls[c][r][e1];
            atomicAdd(ws + SUMS_OFF + (n * C_CLS + c) * E_DIM + e0 + e1, s);
        }
        if (eg == 0) {
            for (int c = tid; c < C_CLS; c += 256) {
                float s = 0.f;
#pragma unroll
                for (int r = 0; r < NREP; r++) s += ls[c][r][EG];
                atomicAdd(ws + CNT_OFF + n * C_CLS + c, s);
            }
        }
    }

    if (mode == 3) cg::this_grid().sync();

    if (mode & 2) {
        // ---------- phase 2: means -> push/reg terms + variance (pull) term ----------
        const int n = b & 3;
        const int s2 = b >> 2;                    // 0..255
        const float* gsum = ws + SUMS_OFF + n * C_CLS * E_DIM;
        const float* gcnt = ws + CNT_OFF + n * C_CLS;

        for (int i = tid; i < C_CLS * E_DIM; i += 256) {
            const int c = i >> 4, e = i & 15;
            const float cnt = gcnt[c];
            lmean[c * MSTRIDE + e] = (cnt > 0.f) ? gsum[i] / cnt : 0.f;
        }
        if (tid < C_CLS) {
            const float cnt = gcnt[tid];
            // lw[0] = 0 masks IGNORE pixels branchlessly
            lw[tid] = (tid != 0 && cnt > 0.f) ? 1.0f / (cnt * (float)CK) : 0.f;
        }
        __syncthreads();

        float acc = 0.f;
        if (b < N_IMG) {
            // blocks 0..3 (one per image) also compute distance + regularizer terms
            for (int idx = tid; idx < CK * CK; idx += 256) {
                const int i = idx / CK + 1, j = idx % CK + 1;
                if (i != j) {
                    float sq = 0.f;
#pragma unroll
                    for (int e = 0; e < E_DIM; e++) {
                        const float d = lmean[i * MSTRIDE + e] - lmean[j * MSTRIDE + e];
                        sq += d * d;
                    }
                    const float dm = sqrtf(sq);
                    const float h = fmaxf(3.0f - dm, 0.f);   // 2*DELTA_DIST = 3
                    acc += h * h;
                }
            }
            acc *= 1.0f / (float)(CK * (CK - 1));            // BETA = 1
            float racc = 0.f;
            for (int c = tid + 1; c < C_CLS; c += 256) {
                float sq = 0.f;
#pragma unroll
                for (int e = 0; e < E_DIM; e++) {
                    const float m = lmean[c * MSTRIDE + e];
                    sq += m * m;
                }
                racc += sqrtf(sq);
            }
            acc += 0.001f * racc / (float)CK;                // GAMMA = 0.001
        }

        const float4* emb4 = (const float4*)emb + (size_t)n * E_DIM * G_PIX;
        const int4* tgt4 = (const int4*)target + (size_t)n * G_PIX;
        const int gend0 = (s2 + 1) * R2;
        const int gend = (gend0 < G_PIX) ? gend0 : G_PIX;
        for (int g = s2 * R2 + tid; g < gend; g += 256) {
            const int4 lb = tgt4[g];
            const int bx = lb.x * MSTRIDE, by = lb.y * MSTRIDE;
            const int bz = lb.z * MSTRIDE, bw = lb.w * MSTRIDE;
            float sx = 0.f, sy = 0.f, sz = 0.f, sw = 0.f;
#pragma unroll
            for (int e = 0; e < E_DIM; e++) {
                const float4 v = emb4[(size_t)e * G_PIX + g];
                float d;
                d = v.x - lmean[bx + e]; sx += d * d;
                d = v.y - lmean[by + e]; sy += d * d;
                d = v.z - lmean[bz + e]; sz += d * d;
                d = v.w - lmean[bw + e]; sw += d * d;
            }
            float h;
            h = fmaxf(sqrtf(sx) - 0.5f, 0.f); acc += h * h * lw[lb.x];
            h = fmaxf(sqrtf(sy) - 0.5f, 0.f); acc += h * h * lw[lb.y];
            h = fmaxf(sqrtf(sz) - 0.5f, 0.f); acc += h * h * lw[lb.z];
            h = fmaxf(sqrtf(sw) - 0.5f, 0.f); acc += h * h * lw[lb.w];
        }

        red[tid] = acc;
        __syncthreads();
        for (int s = 128; s > 0; s >>= 1) {
            if (tid < s) red[tid] += red[tid + s];
            __syncthreads();
        }
        if (tid == 0) atomicAdd(ws + LOSS_OFF, red[0]);

        if (mode == 3) {
            cg::this_grid().sync();
            if (b == 0 && tid == 0) out[0] = ws[LOSS_OFF] * 0.25f;  // mean over 4 images
        }
    }
}

// fallback finalizer (non-cooperative path only)
__global__ void k_fin2(const float* __restrict__ ws, float* __restrict__ out) {
    out[0] = ws[LOSS_OFF] * 0.25f;
}

extern "C" void kernel_launch(void* const* d_in, const int* in_sizes, int n_in,
                              void* d_out, int out_size, void* d_ws, size_t ws_size,
                              hipStream_t stream) {
    const float* emb = (const float*)d_in[0];
    const int* target = (const int*)d_in[1];
    float* out = (float*)d_out;
    float* ws = (float*)d_ws;

    hipMemsetAsync(d_ws, 0, WS_FLOATS * sizeof(float), stream);

    int mode = 3;
    void* args[] = {(void*)&emb, (void*)&target, (void*)&ws, (void*)&out, (void*)&mode};
    hipError_t err = hipLaunchCooperativeKernel((void*)k_fused, dim3(GRID_B), dim3(256),
                                                args, 0, stream);
    if (err != hipSuccess) {
        // fallback: same kernel as two ordinary launches + finalizer
        k_fused<<<dim3(GRID_B), 256, 0, stream>>>(emb, target, ws, out, 1);
        k_fused<<<dim3(GRID_B), 256, 0, stream>>>(emb, target, ws, out, 2);
        k_fin2<<<1, 1, 0, stream>>>(ws, out);
    }
}

// Round 3
// 153.147 us; speedup vs baseline: 2.7445x; 2.7445x over previous
//
#include <hip/hip_runtime.h>

#define N_IMG 4
#define E_DIM 16
#define G_PIX 80000               // float4 groups per image-channel (320000/4)
#define C_CLS 20
#define CK 19                     // classes 1..19 (IGNORE = 0)
#define NREP 8                    // LDS replica count for atomic binning
#define EG 4                      // channels per k_sums block
#define NEG (E_DIM / EG)          // 4 channel groups
#define SL1 64                    // pixel slices per (image, egroup)
#define R1 (G_PIX / SL1)          // 1250 groups per k_sums block (exact)
#define GRID1 (SL1 * NEG * N_IMG) // 1024 blocks = 4 per CU
#define SL2 256                   // k_var slices per image
#define R2 ((G_PIX + SL2 - 1) / SL2) // 313 (tail-checked)
#define GRID2 (SL2 * N_IMG)       // 1024 blocks
#define MSTRIDE 17                // lmean stride: 20 labels -> 20 distinct banks
#define LS_SLOT 5                 // u64 slots per (class, replica): stride 5 -> 16 bank-pairs
#define SCALE_F 16777216.0f       // 2^24 fixed-point scale
#define INV_SCALE (1.0f / 16777216.0f)

// ws float layout: sums[n][c][e], counts[n][c], loss
#define SUMS_OFF 0
#define CNT_OFF (N_IMG * C_CLS * E_DIM)       // 1280
#define LOSS_OFF (CNT_OFF + N_IMG * C_CLS)    // 1360
#define WS_FLOATS (LOSS_OFF + 1)

static_assert(G_PIX % SL1 == 0, "k_sums slicing must be exact");

// ---------------- Kernel 1: per-class sums + counts via native integer LDS atomics ----------
// NOTE: float LDS atomicAdd compiles to a CAS loop on gfx950 (measured: 310us vs 65us).
// Integer ds_add_u64 is native + fire-and-forget; values quantized at 2^24 fixed point.
__global__ __launch_bounds__(256, 4) void k_sums(const float* __restrict__ emb,
                                                 const int* __restrict__ target,
                                                 float* __restrict__ ws) {
    __shared__ unsigned long long ls[C_CLS][NREP][LS_SLOT];   // 6400 B
    __shared__ unsigned int lc[C_CLS][NREP];                  // 640 B

    const int tid = threadIdx.x;
    const int b = blockIdx.x;
    const int n = b & 3;
    const int eg = (b >> 2) & (NEG - 1);
    const int slice = b >> 4;                  // 0..SL1-1
    const int e0 = eg * EG;

    unsigned long long* lsf = &ls[0][0][0];
    for (int i = tid; i < C_CLS * NREP * LS_SLOT; i += 256) lsf[i] = 0ull;
    for (int i = tid; i < C_CLS * NREP; i += 256) (&lc[0][0])[i] = 0u;
    __syncthreads();

    const float4* emb0 = (const float4*)emb + ((size_t)(n * E_DIM + e0)) * G_PIX;
    const int4* tgt4 = (const int4*)target + (size_t)n * G_PIX;
    const int r = tid & (NREP - 1);

#define QADD(p, idx, val) \
    atomicAdd((p) + (idx), (unsigned long long)(long long)__float2int_rn((val) * SCALE_F))

    const int g1 = (slice + 1) * R1;
    for (int g = slice * R1 + tid; g < g1; g += 256) {
        const int4 lb = tgt4[g];
        const float4 v0 = emb0[g];
        const float4 v1 = emb0[G_PIX + g];
        const float4 v2 = emb0[2 * G_PIX + g];
        const float4 v3 = emb0[3 * G_PIX + g];

        unsigned long long* px = &ls[lb.x][r][0];
        unsigned long long* py = &ls[lb.y][r][0];
        unsigned long long* pz = &ls[lb.z][r][0];
        unsigned long long* pw = &ls[lb.w][r][0];
        QADD(px, 0, v0.x); QADD(px, 1, v1.x); QADD(px, 2, v2.x); QADD(px, 3, v3.x);
        QADD(py, 0, v0.y); QADD(py, 1, v1.y); QADD(py, 2, v2.y); QADD(py, 3, v3.y);
        QADD(pz, 0, v0.z); QADD(pz, 1, v1.z); QADD(pz, 2, v2.z); QADD(pz, 3, v3.z);
        QADD(pw, 0, v0.w); QADD(pw, 1, v1.w); QADD(pw, 2, v2.w); QADD(pw, 3, v3.w);
        if (eg == 0) {
            atomicAdd(&lc[lb.x][r], 1u); atomicAdd(&lc[lb.y][r], 1u);
            atomicAdd(&lc[lb.z][r], 1u); atomicAdd(&lc[lb.w][r], 1u);
        }
    }
#undef QADD
    __syncthreads();

    // flush: combine replicas, convert back to float, one global atomic per (c, e')
    for (int i = tid; i < C_CLS * EG; i += 256) {
        const int c = i >> 2, e1 = i & 3;
        long long q = 0;
#pragma unroll
        for (int rr = 0; rr < NREP; rr++) q += (long long)ls[c][rr][e1];
        atomicAdd(ws + SUMS_OFF + (n * C_CLS + c) * E_DIM + e0 + e1, (float)q * INV_SCALE);
    }
    if (eg == 0) {
        for (int c = tid; c < C_CLS; c += 256) {
            unsigned int s = 0;
#pragma unroll
            for (int rr = 0; rr < NREP; rr++) s += lc[c][rr];
            atomicAdd(ws + CNT_OFF + n * C_CLS + c, (float)s);
        }
    }
}

// -------- Kernel 2: means (per-block) + distance/reg terms (blocks 0..3) + variance term ----
__global__ __launch_bounds__(256, 4) void k_var(const float* __restrict__ emb,
                                                const int* __restrict__ target,
                                                float* __restrict__ ws) {
    __shared__ float lmean[C_CLS * MSTRIDE];
    __shared__ float lw[C_CLS];
    __shared__ float red[256];

    const int tid = threadIdx.x;
    const int b = blockIdx.x;
    const int n = b & 3;
    const int s2 = b >> 2;                     // 0..SL2-1

    const float* gsum = ws + SUMS_OFF + n * C_CLS * E_DIM;
    const float* gcnt = ws + CNT_OFF + n * C_CLS;

    for (int i = tid; i < C_CLS * E_DIM; i += 256) {
        const int c = i >> 4, e = i & 15;
        const float cnt = gcnt[c];
        lmean[c * MSTRIDE + e] = (cnt > 0.f) ? gsum[i] / cnt : 0.f;
    }
    if (tid < C_CLS) {
        const float cnt = gcnt[tid];
        // lw[0] = 0 masks IGNORE pixels branchlessly
        lw[tid] = (tid != 0 && cnt > 0.f) ? 1.0f / (cnt * (float)CK) : 0.f;
    }
    __syncthreads();

    float acc = 0.f;
    if (b < N_IMG) {
        // one block per image computes push + regularizer terms
        for (int idx = tid; idx < CK * CK; idx += 256) {
            const int i = idx / CK + 1, j = idx % CK + 1;
            if (i != j) {
                float sq = 0.f;
#pragma unroll
                for (int e = 0; e < E_DIM; e++) {
                    const float d = lmean[i * MSTRIDE + e] - lmean[j * MSTRIDE + e];
                    sq += d * d;
                }
                const float dm = sqrtf(sq);
                const float h = fmaxf(3.0f - dm, 0.f);   // 2*DELTA_DIST = 3
                acc += h * h;
            }
        }
        acc *= 1.0f / (float)(CK * (CK - 1));            // BETA = 1
        float racc = 0.f;
        for (int c = tid + 1; c < C_CLS; c += 256) {
            float sq = 0.f;
#pragma unroll
            for (int e = 0; e < E_DIM; e++) {
                const float m = lmean[c * MSTRIDE + e];
                sq += m * m;
            }
            racc += sqrtf(sq);
        }
        acc += 0.001f * racc / (float)CK;                // GAMMA = 0.001
    }

    const float4* emb4 = (const float4*)emb + (size_t)n * E_DIM * G_PIX;
    const int4* tgt4 = (const int4*)target + (size_t)n * G_PIX;
    const int gend0 = (s2 + 1) * R2;
    const int gend = (gend0 < G_PIX) ? gend0 : G_PIX;
    for (int g = s2 * R2 + tid; g < gend; g += 256) {
        const int4 lb = tgt4[g];
        const int bx = lb.x * MSTRIDE, by = lb.y * MSTRIDE;
        const int bz = lb.z * MSTRIDE, bw = lb.w * MSTRIDE;
        float sx = 0.f, sy = 0.f, sz = 0.f, sw = 0.f;
#pragma unroll
        for (int e = 0; e < E_DIM; e++) {
            const float4 v = emb4[(size_t)e * G_PIX + g];
            float d;
            d = v.x - lmean[bx + e]; sx += d * d;
            d = v.y - lmean[by + e]; sy += d * d;
            d = v.z - lmean[bz + e]; sz += d * d;
            d = v.w - lmean[bw + e]; sw += d * d;
        }
        float h;
        h = fmaxf(sqrtf(sx) - 0.5f, 0.f); acc += h * h * lw[lb.x];
        h = fmaxf(sqrtf(sy) - 0.5f, 0.f); acc += h * h * lw[lb.y];
        h = fmaxf(sqrtf(sz) - 0.5f, 0.f); acc += h * h * lw[lb.z];
        h = fmaxf(sqrtf(sw) - 0.5f, 0.f); acc += h * h * lw[lb.w];
    }

    red[tid] = acc;
    __syncthreads();
    for (int s = 128; s > 0; s >>= 1) {
        if (tid < s) red[tid] += red[tid + s];
        __syncthreads();
    }
    if (tid == 0) atomicAdd(ws + LOSS_OFF, red[0]);
}

// ---------------- Kernel 3: finalize ----------------
__global__ void k_fin(const float* __restrict__ ws, float* __restrict__ out) {
    out[0] = ws[LOSS_OFF] * 0.25f;  // mean over 4 images
}

extern "C" void kernel_launch(void* const* d_in, const int* in_sizes, int n_in,
                              void* d_out, int out_size, void* d_ws, size_t ws_size,
                              hipStream_t stream) {
    const float* emb = (const float*)d_in[0];
    const int* target = (const int*)d_in[1];
    float* out = (float*)d_out;
    float* ws = (float*)d_ws;

    hipMemsetAsync(d_ws, 0, WS_FLOATS * sizeof(float), stream);
    k_sums<<<dim3(GRID1), 256, 0, stream>>>(emb, target, ws);
    k_var<<<dim3(GRID2), 256, 0, stream>>>(emb, target, ws);
    k_fin<<<1, 1, 0, stream>>>(ws, out);
}